// Round 12
// baseline (826.342 us; speedup 1.0000x reference)
//
#include <hip/hip_runtime.h>
#include <math.h>

// Problem constants
constexpr int Cc = 128;          // channels
constexpr int Dd = 48, Hh = 48, Ww = 48;
constexpr int SP = Dd * Hh * Ww; // 110592 voxels per batch
constexpr int NV = 2 * SP;       // 221184 total voxels
constexpr float EPSV = 1e-5f;

typedef __attribute__((ext_vector_type(8))) short short8;
typedef __attribute__((ext_vector_type(4))) float f32x4;

static __device__ __forceinline__ ushort f2bf(float f) {
    uint u = __float_as_uint(f);
    uint r = (u + 0x7fffu + ((u >> 16) & 1u)) >> 16;   // RNE
    return (ushort)r;
}

// ---------------------------------------------------------------- prep
__global__ void k_prep(const float* __restrict__ th, const float* __restrict__ ph,
                       const float* __restrict__ gw, const float* __restrict__ rw,
                       ushort* __restrict__ wtb, ushort* __restrict__ rwh,
                       ushort* __restrict__ rwl) {
    int tid = threadIdx.x;
    for (int i = tid; i < 192 * 128; i += 256) {
        int o = i >> 7, c = i & 127;
        float v = (o < 64)  ? th[o * 128 + c]
                : (o < 128) ? ph[(o - 64) * 128 + c]
                            : gw[(o - 128) * 128 + c];
        wtb[i] = f2bf(v);
    }
    // rW hi/lo split, [c][g] layout (same as input r_w)
    for (int i = tid; i < 128 * 64; i += 256) {
        float v = rw[i];
        ushort hh = f2bf(v);
        rwh[i] = hh;
        rwl[i] = f2bf(v - __uint_as_float((uint)hh << 16));
    }
}

// ---------------------------------------------------------------- projections (MFMA)
// 128 voxels/block, 512 threads. OPERAND-SWAPPED: D[o][vox] = W.H so each lane
// holds 4 consecutive output channels of ONE voxel -> packed 8B stores (12/lane)
// instead of 48 scalar 2B stores. Load paths identical to previous version
// (fragment layouts are symmetric: A row-indexed, B col-indexed by lane&15).
__global__ __launch_bounds__(512) void k_proj(
        const float* __restrict__ h, const ushort* __restrict__ wtb,
        const float* __restrict__ tb, const float* __restrict__ pb,
        const float* __restrict__ gb,
        ushort* __restrict__ tO, ushort* __restrict__ pO, ushort* __restrict__ gO) {
    __shared__ __align__(16) uint wl[192 * 64];   // 48 KB, [o][c-pairs] swizzled
    int tid = threadIdx.x;
    const uint* wu = (const uint*)wtb;
    for (int i = tid; i < 192 * 64; i += 512) {
        int o = i >> 6, dw = i & 63;
        wl[(o << 6) + ((((dw >> 2) ^ (o & 15)) << 2)) + (dw & 3)] = wu[i];
    }
    int blk = blockIdx.x;                         // 1728
    int b = blk / (SP / 128);
    int vsp0 = (blk % (SP / 128)) * 128;
    const float* hb = h + (size_t)b * Cc * SP;
    int lane = tid & 63, wv = tid >> 6;           // wv 0..7
    int m = lane & 15, quad = lane >> 4;
    int vg = vsp0 + wv * 16 + m;
    short8 hfr[4];                                // B-operand: H[k=ch][col=vox m]
#pragma unroll
    for (int ks = 0; ks < 4; ++ks) {
        int c0 = ks * 32 + quad * 8;
        float xv[8];
#pragma unroll
        for (int j = 0; j < 8; ++j) xv[j] = hb[(size_t)(c0 + j) * SP + vg];
        union { short8 v; ushort e[8]; } u;
#pragma unroll
        for (int j = 0; j < 8; ++j) u.e[j] = f2bf(xv[j]);
        hfr[ks] = u.v;
    }
    __syncthreads();
    size_t vox = (size_t)(b * SP + vsp0 + wv * 16 + m);
#pragma unroll 1
    for (int nt = 0; nt < 12; ++nt) {
        const float* bias = (nt < 4) ? tb : (nt < 8) ? pb : gb;
        int o0 = (nt & 3) * 16 + quad * 4;
        f32x4 acc = {bias[o0], bias[o0 + 1], bias[o0 + 2], bias[o0 + 3]};
        int o = nt * 16 + m;
#pragma unroll
        for (int ks = 0; ks < 4; ++ks) {
            int chunk = ks * 4 + quad;
            short8 wfr = *(const short8*)&wl[(o << 6) + ((chunk ^ (o & 15)) << 2)];
            acc = __builtin_amdgcn_mfma_f32_16x16x32_bf16(wfr, hfr[ks], acc, 0, 0, 0);
        }
        ushort* ob = (nt < 4) ? tO : (nt < 8) ? pO : gO;
        uint2 pk;
        pk.x = (uint)f2bf(acc[0]) | ((uint)f2bf(acc[1]) << 16);
        pk.y = (uint)f2bf(acc[2]) | ((uint)f2bf(acc[3]) << 16);
        *(uint2*)&ob[vox * 64 + o0] = pk;
    }
}

// ---------------------------------------------------------------- scores (MFMA, 3 axes)
// Writes E = bf16(exp(S)) directly (masked diag -> 0) + per-row sums PS = sum(e).
// ysum loads E fragments straight from global; normalization applied in k_cross.
__global__ __launch_bounds__(256) void k_scores(
        const ushort* __restrict__ t, const ushort* __restrict__ p,
        ushort* __restrict__ fb16, float* __restrict__ PS) {
    __shared__ __align__(16) uint sl[4 * 3072];
    int blk = blockIdx.x;                         // 3456 = 3 axes * 1152
    int axis = blk / 1152, rem = blk % 1152;
    int wv = threadIdx.x >> 6, lane = threadIdx.x & 63;
    int L = rem * 4 + wv;
    int b = L / 2304, rr = L % 2304, i = rr / 48, j = rr % 48;
    int stride, vsp0;
    if (axis == 0)      { stride = 2304; vsp0 = i * 48 + j; }
    else if (axis == 1) { stride = 48;   vsp0 = i * 2304 + j; }
    else                { stride = 1;    vsp0 = i * 2304 + j * 48; }
    int vox0 = b * SP + vsp0;
    ushort* f = fb16 + (size_t)axis * NV * 48;
    float* ps = PS + (size_t)axis * NV;
    uint* tl = &sl[wv * 3072];
    uint* pl = tl + 1536;
    const uint* tu = (const uint*)t;
    const uint* pu = (const uint*)p;
#pragma unroll 4
    for (int it = 0; it < 24; ++it) {
        int idx = it * 64 + lane;
        int r = idx >> 5, dw = idx & 31;
        int gaddr = (vox0 + r * stride) * 32 + dw;
        int laddr = (r << 5) + (((dw >> 2) ^ (r & 7)) << 2) + (dw & 3);
        tl[laddr] = tu[gaddr];
        pl[laddr] = pu[gaddr];
    }
    __syncthreads();
    int m = lane & 15, quad = lane >> 4;
    short8 afr[3][2];
#pragma unroll
    for (int mt = 0; mt < 3; ++mt)
#pragma unroll
        for (int ks = 0; ks < 2; ++ks) {
            int r = mt * 16 + m, chunk = ks * 4 + quad;
            afr[mt][ks] = *(const short8*)&tl[(r << 5) + ((chunk ^ (r & 7)) << 2)];
        }
    f32x4 acc[3][3];
#pragma unroll
    for (int mt = 0; mt < 3; ++mt)
#pragma unroll
        for (int nt = 0; nt < 3; ++nt) acc[mt][nt] = (f32x4){0.f, 0.f, 0.f, 0.f};
#pragma unroll
    for (int nt = 0; nt < 3; ++nt)
#pragma unroll
        for (int ks = 0; ks < 2; ++ks) {
            int a = nt * 16 + m, chunk = ks * 4 + quad;
            short8 bfr = *(const short8*)&pl[(a << 5) + ((chunk ^ (a & 7)) << 2)];
#pragma unroll
            for (int mt = 0; mt < 3; ++mt)
                acc[mt][nt] = __builtin_amdgcn_mfma_f32_16x16x32_bf16(
                    afr[mt][ks], bfr, acc[mt][nt], 0, 0, 0);
        }
    bool mask = (axis != 0);
    float esum[3][4];
#pragma unroll
    for (int mt = 0; mt < 3; ++mt)
#pragma unroll
        for (int r4 = 0; r4 < 4; ++r4) esum[mt][r4] = 0.f;
#pragma unroll
    for (int mt = 0; mt < 3; ++mt)
#pragma unroll
        for (int nt = 0; nt < 3; ++nt)
#pragma unroll
            for (int r4 = 0; r4 < 4; ++r4) {
                int r = mt * 16 + quad * 4 + r4;
                int a = nt * 16 + m;
                float e = (mask && a == r) ? 0.f : __expf(acc[mt][nt][r4]);
                f[(size_t)(vox0 + r * stride) * 48 + a] = f2bf(e);
                esum[mt][r4] += e;
            }
    // per-row exp-sum: reduce across the 16 lanes (m) of each quad-group
#pragma unroll
    for (int mt = 0; mt < 3; ++mt)
#pragma unroll
        for (int r4 = 0; r4 < 4; ++r4) {
            float s = esum[mt][r4];
#pragma unroll
            for (int o = 8; o; o >>= 1) s += __shfl_xor(s, o, 64);
            if (m == 0) {
                int r = mt * 16 + quad * 4 + r4;
                ps[vox0 + r * stride] = s;
            }
        }
}

// ---------------------------------------------------------------- weighted sum (MFMA)
// Y'[48x64] (+)= E[48x48] . G[48x64] per line (UNNORMALIZED; inv applied in k_cross).
// E fragments loaded DIRECTLY from global (16B-aligned, L2-hot; K-pad chunks -> 0).
// Only G (true transpose gather) stages through LDS: 8KB/wave.
__global__ __launch_bounds__(128) void k_ysum(
        const ushort* __restrict__ wgt, const ushort* __restrict__ g,
        float* __restrict__ y, int axis, int accum) {
    __shared__ __align__(16) uint sl[2 * 2048];   // per-wave gl 2048 dw (8 KB)
    int wv = threadIdx.x >> 6, lane = threadIdx.x & 63;
    uint* gl = &sl[wv * 2048];
    int L = blockIdx.x * 2 + wv;                  // 0..4607
    int b = L / 2304, rr = L % 2304, i = rr / 48, j = rr % 48;
    int stride, vsp0;
    if (axis == 0)      { stride = 2304; vsp0 = i * 48 + j; }
    else if (axis == 1) { stride = 48;   vsp0 = i * 2304 + j; }
    else                { stride = 1;    vsp0 = i * 2304 + j * 48; }
    int vox0 = b * SP + vsp0;
    int m = lane & 15, quad = lane >> 4;
    // E fragments direct from global: row r, cols chunk*8..+7 (16B aligned: r*96+chunk*16)
    short8 afr[3][2];
#pragma unroll
    for (int mt = 0; mt < 3; ++mt)
#pragma unroll
        for (int ks = 0; ks < 2; ++ks) {
            int chunk = ks * 4 + quad;
            short8 v = (short8){0, 0, 0, 0, 0, 0, 0, 0};
            if (chunk < 6) {
                int r = mt * 16 + m;
                v = *(const short8*)&wgt[(size_t)(vox0 + r * stride) * 48 + chunk * 8];
            }
            afr[mt][ks] = v;
        }
    // gl zero-pad chunks 6,7 (a>=48): avoid 0 x stale-NaN = NaN
#pragma unroll
    for (int it = 0; it < 8; ++it) {
        int idx = it * 64 + lane;
        int s = idx >> 3, dwp = 24 + (idx & 7);
        gl[(s << 5) + ((((dwp >> 2)) ^ (s & 7)) << 2) + (dwp & 3)] = 0;
    }
    // G transpose staging: read [a][s-pairs] dwords, shfl-pair a/a^1, write [s][a-pairs]
    const uint* gu = (const uint*)g;
#pragma unroll 4
    for (int it = 0; it < 24; ++it) {
        int a = it * 2 + (lane >> 5);
        int dw = lane & 31;
        uint v = gu[(size_t)(vox0 + a * stride) * 32 + dw];
        uint w = (uint)__shfl_xor((int)v, 32, 64);
        uint dst; int s;
        if (lane < 32) { s = dw * 2;     dst = (v & 0xffffu) | (w << 16); }
        else           { s = dw * 2 + 1; dst = (w >> 16) | (v & 0xffff0000u); }
        int adw = it;
        gl[(s << 5) + ((((adw >> 2)) ^ (s & 7)) << 2) + (adw & 3)] = dst;
    }
    // per-wave LDS slice: no __syncthreads needed (in-wave DS ordering)
    f32x4 acc[3][4];
#pragma unroll
    for (int mt = 0; mt < 3; ++mt)
#pragma unroll
        for (int nt = 0; nt < 4; ++nt) acc[mt][nt] = (f32x4){0.f, 0.f, 0.f, 0.f};
#pragma unroll
    for (int nt = 0; nt < 4; ++nt)
#pragma unroll
        for (int ks = 0; ks < 2; ++ks) {
            int s = nt * 16 + m, chunk = ks * 4 + quad;
            short8 bfr = *(const short8*)&gl[(s << 5) + ((chunk ^ (s & 7)) << 2)];
#pragma unroll
            for (int mt = 0; mt < 3; ++mt)
                acc[mt][nt] = __builtin_amdgcn_mfma_f32_16x16x32_bf16(
                    afr[mt][ks], bfr, acc[mt][nt], 0, 0, 0);
        }
#pragma unroll
    for (int mt = 0; mt < 3; ++mt)
#pragma unroll
        for (int r4 = 0; r4 < 4; ++r4) {
            int r = mt * 16 + quad * 4 + r4;
#pragma unroll
            for (int nt = 0; nt < 4; ++nt) {
                size_t addr = (size_t)(vox0 + r * stride) * 64 + nt * 16 + m;
                float pr = accum ? y[addr] : 0.f;
                y[addr] = pr + acc[mt][nt][r4];
            }
        }
}

// ---------------------------------------------------------------- cross proj (MFMA, hi/lo bf16)
// A-rows normalized on load: y_row * 1/(PS0+PS1+PS2). + fused GN partials -> gp.
__global__ __launch_bounds__(256) void k_cross(
        const float* __restrict__ y, const float* __restrict__ PS,
        const ushort* __restrict__ rwh, const ushort* __restrict__ rwl,
        const float* __restrict__ rb,
        float* __restrict__ cross, float* __restrict__ gp) {
    __shared__ __align__(16) uint sl[8192];       // 32 KB
    int tid = threadIdx.x;
    int blk = blockIdx.x;                         // 3456
    int b = blk / (SP / 64);
    int sp64 = blk % (SP / 64);                   // 0..1727
    int vsp0 = sp64 * 64;
    long vox0 = (long)b * SP + vsp0;
    const uint* wh = (const uint*)rwh;
    const uint* wlg = (const uint*)rwl;
    for (int i = tid; i < 8192; i += 256) {
        int t = i >> 12, rr = (i >> 5) & 127, dw = i & 31;
        uint v = (t == 0) ? wh[rr * 32 + dw] : wlg[rr * 32 + dw];
        sl[(t << 12) + (rr << 5) + (((dw >> 2) ^ (rr & 7)) << 2) + (dw & 3)] = v;
    }
    int lane = tid & 63, wv = tid >> 6;
    int m = lane & 15, quad = lane >> 4;
    short8 ah[2], al[2];
    long vrow = vox0 + wv * 16 + m;
    const float* yrow = y + vrow * 64;
    float iv = 1.f / (PS[vrow] + PS[NV + vrow] + PS[2 * NV + vrow]);
#pragma unroll
    for (int ks = 0; ks < 2; ++ks) {
        float4 v0 = *(const float4*)(yrow + ks * 32 + quad * 8);
        float4 v1 = *(const float4*)(yrow + ks * 32 + quad * 8 + 4);
        float xv[8] = {v0.x * iv, v0.y * iv, v0.z * iv, v0.w * iv,
                       v1.x * iv, v1.y * iv, v1.z * iv, v1.w * iv};
        union { short8 v; ushort e[8]; } uh, ul;
#pragma unroll
        for (int j = 0; j < 8; ++j) {
            ushort hh = f2bf(xv[j]);
            uh.e[j] = hh;
            ul.e[j] = f2bf(xv[j] - __uint_as_float((uint)hh << 16));
        }
        ah[ks] = uh.v; al[ks] = ul.v;
    }
    f32x4 acc[8];
#pragma unroll
    for (int nt = 0; nt < 8; ++nt) {
        float bv = rb[nt * 16 + m];
        acc[nt] = (f32x4){bv, bv, bv, bv};
    }
    __syncthreads();
#pragma unroll
    for (int nt = 0; nt < 8; ++nt) {
        int r = nt * 16 + m;
#pragma unroll
        for (int ks = 0; ks < 2; ++ks) {
            int chunk = ks * 4 + quad;
            int off = (r << 5) + ((chunk ^ (r & 7)) << 2);
            short8 bh = *(const short8*)&sl[off];
            short8 bl = *(const short8*)&sl[4096 + off];
            acc[nt] = __builtin_amdgcn_mfma_f32_16x16x32_bf16(ah[ks], bh, acc[nt], 0, 0, 0);
            acc[nt] = __builtin_amdgcn_mfma_f32_16x16x32_bf16(al[ks], bh, acc[nt], 0, 0, 0);
            acc[nt] = __builtin_amdgcn_mfma_f32_16x16x32_bf16(ah[ks], bl, acc[nt], 0, 0, 0);
        }
    }
    __syncthreads();
    int sv = wv * 4 + quad;
#pragma unroll
    for (int nt = 0; nt < 8; ++nt) {
        int c = nt * 16 + m;
        *(f32x4*)&sl[((c << 4) | (sv ^ (c & 15))) << 2] = acc[nt];
    }
    __syncthreads();
#pragma unroll
    for (int it = 0; it < 8; ++it) {
        int idx = it * 256 + tid;
        int c = idx >> 4, s16 = idx & 15;
        float4 val = *(const float4*)&sl[((c << 4) | (s16 ^ (c & 15))) << 2];
        *(float4*)&cross[((long)b * Cc + c) * SP + vsp0 + s16 * 4] = val;
        float s  = val.x + val.y + val.z + val.w;
        float ss = val.x * val.x + val.y * val.y + val.z * val.z + val.w * val.w;
#pragma unroll
        for (int o = 32; o; o >>= 1) { s += __shfl_xor(s, o, 64); ss += __shfl_xor(ss, o, 64); }
        if (lane == 0) {
            int bg = b * 32 + it * 4 + wv;
            gp[(size_t)(bg * 2) * 1728 + sp64] = s;
            gp[(size_t)(bg * 2 + 1) * 1728 + sp64] = ss;
        }
    }
}

// ---------------------------------------------------------------- GN reduce (scatter -> stats)
__global__ __launch_bounds__(256) void k_gnred(
        const float* __restrict__ gp, float* __restrict__ stats) {
    int g = blockIdx.x;          // 64
    const float* r0 = gp + (size_t)(g * 2) * 1728;
    const float* r1 = r0 + 1728;
    float s = 0.f, ss = 0.f;
    for (int t = threadIdx.x; t < 1728; t += 256) { s += r0[t]; ss += r1[t]; }
#pragma unroll
    for (int o = 32; o; o >>= 1) { s += __shfl_xor(s, o, 64); ss += __shfl_xor(ss, o, 64); }
    __shared__ float rs[4], rss[4];
    int wv = threadIdx.x >> 6;
    if ((threadIdx.x & 63) == 0) { rs[wv] = s; rss[wv] = ss; }
    __syncthreads();
    if (threadIdx.x == 0) {
        float S = rs[0] + rs[1] + rs[2] + rs[3];
        float SS = rss[0] + rss[1] + rss[2] + rss[3];
        float n = 4.f * SP;
        float mu = S / n, var = SS / n - mu * mu;
        stats[g * 2] = mu;
        stats[g * 2 + 1] = rsqrtf(var + EPSV);
    }
}

// ---------------------------------------------------------------- GN apply (+ BN partial scatter)
__global__ __launch_bounds__(256) void k_gnapply(
        const float* __restrict__ hin, const float* __restrict__ cross,
        const float* __restrict__ stats, const float* __restrict__ gw,
        const float* __restrict__ gb, float* __restrict__ hout,
        float* __restrict__ bp, int doBN) {
    __shared__ float rs[4], rss[4];
    long q = ((long)blockIdx.x * 256 + threadIdx.x) * 4;
    int c = (int)((q / SP) & 127);
    int b = (int)(q / ((long)Cc * SP));
    int bg = b * 32 + (c >> 2);
    float mu = stats[bg * 2], inv = stats[bg * 2 + 1];
    float sc = inv * gw[c], sh = gb[c] - mu * sc;
    float4 cv = *(const float4*)(cross + q);
    float4 hv = *(const float4*)(hin + q);
    float4 o = make_float4(hv.x + cv.x * sc + sh, hv.y + cv.y * sc + sh,
                           hv.z + cv.z * sc + sh, hv.w + cv.w * sc + sh);
    *(float4*)(hout + q) = o;
    if (doBN) {
        float s  = o.x + o.y + o.z + o.w;
        float ss = o.x * o.x + o.y * o.y + o.z * o.z + o.w * o.w;
#pragma unroll
        for (int off = 32; off; off >>= 1) { s += __shfl_xor(s, off, 64); ss += __shfl_xor(ss, off, 64); }
        if ((threadIdx.x & 63) == 0) { rs[threadIdx.x >> 6] = s; rss[threadIdx.x >> 6] = ss; }
        __syncthreads();
        if (threadIdx.x == 0) {
            float S = rs[0] + rs[1] + rs[2] + rs[3];
            float SS = rss[0] + rss[1] + rss[2] + rss[3];
            int l = blockIdx.x % 108;             // 108 blocks per (b,c)
            int contrib = b * 108 + l;            // 0..215
            bp[(size_t)(c * 2) * 216 + contrib] = S;
            bp[(size_t)(c * 2 + 1) * 216 + contrib] = SS;
        }
    }
}

// ---------------------------------------------------------------- BN finalize (scatter -> scale/shift)
__global__ void k_bnfin(const float* __restrict__ bp, const float* __restrict__ bw,
                        const float* __restrict__ bb, float* __restrict__ ssout) {
    __shared__ float rows[256];
    int tid = threadIdx.x;   // 256: one row of 216 per thread
    float acc = 0.f;
    const float* r = bp + (size_t)tid * 216;
    for (int t = 0; t < 216; ++t) acc += r[t];
    rows[tid] = acc;
    __syncthreads();
    if (tid < 128) {
        float s = rows[tid * 2], qq = rows[tid * 2 + 1];
        float n = 2.f * SP;
        float mu = s / n, var = qq / n - mu * mu;
        float inv = rsqrtf(var + EPSV);
        float a1 = inv * bw[tid];
        ssout[tid * 2] = a1;
        ssout[tid * 2 + 1] = bb[tid] - mu * a1;
    }
}

__global__ __launch_bounds__(256) void k_bnrelu(
        const float* __restrict__ h, const float* __restrict__ ssin,
        float* __restrict__ out) {
    long q = ((long)blockIdx.x * 256 + threadIdx.x) * 4;
    int c = (int)((q / SP) & 127);
    float a1 = ssin[c * 2], a0 = ssin[c * 2 + 1];
    float4 v = *(const float4*)(h + q);
    float4 o = make_float4(fmaxf(v.x * a1 + a0, 0.f), fmaxf(v.y * a1 + a0, 0.f),
                           fmaxf(v.z * a1 + a0, 0.f), fmaxf(v.w * a1 + a0, 0.f));
    *(float4*)(out + q) = o;
}

// ---------------------------------------------------------------- launch
extern "C" void kernel_launch(void* const* d_in, const int* in_sizes, int n_in,
                              void* d_out, int out_size, void* d_ws, size_t ws_size,
                              hipStream_t stream) {
    const float* x   = (const float*)d_in[0];
    const float* thw = (const float*)d_in[1];
    const float* thb = (const float*)d_in[2];
    const float* phw = (const float*)d_in[3];
    const float* phb = (const float*)d_in[4];
    const float* gww = (const float*)d_in[5];
    const float* gwb = (const float*)d_in[6];
    const float* rw  = (const float*)d_in[7];
    const float* rb  = (const float*)d_in[8];
    const float* gnw = (const float*)d_in[9];
    const float* gnb = (const float*)d_in[10];
    const float* bnw = (const float*)d_in[11];
    const float* bnb = (const float*)d_in[12];

    float* ws    = (float*)d_ws;
    ushort* rwh  = (ushort*)ws;               // 8192 bf16 (hi)
    ushort* rwl  = rwh + 8192;                // 8192 bf16 (lo)
    float* stats = ws + 10240;                // 128
    float* bnss  = ws + 10368;                // 256
    ushort* wTb  = (ushort*)(ws + 16384);     // 24576 bf16 ([o][c] row-major)
    ushort* tB16 = (ushort*)(ws + 32768);     // NV*64 bf16
    ushort* pB16 = tB16 + (size_t)NV * 64;
    ushort* gB16 = pB16 + (size_t)NV * 64;
    float* yB    = ws + 32768 + (3 * (size_t)NV * 64) / 2;  // NV*64 fp32
    float* crossB = yB + (size_t)NV * 64;     // NV*128 fp32
    ushort* fb16 = (ushort*)crossB;           // 3*NV*48 bf16 (dead before cross writes)
    float* gp    = crossB + (size_t)NV * 128; // 64*2*1728 fp32 (GN scatter)
    float* bp    = gp + 221184;               // 128*2*216 fp32 (BN scatter)
    float* PS    = bp + 55296;                // 3*NV fp32
    float* out = (float*)d_out;

    k_prep<<<1, 256, 0, stream>>>(thw, phw, gww, rw, wTb, rwh, rwl);

    const float* hin = x;
    for (int layer = 0; layer < 2; ++layer) {
        k_proj<<<NV / 128, 512, 0, stream>>>(hin, wTb, thb, phb, gwb, tB16, pB16, gB16);
        k_scores<<<3456, 256, 0, stream>>>(tB16, pB16, fb16, PS);
        for (int ax = 0; ax < 3; ++ax)
            k_ysum<<<2304, 128, 0, stream>>>(fb16 + (size_t)ax * NV * 48,
                gB16, yB, ax, ax > 0);
        k_cross<<<NV / 64, 256, 0, stream>>>(yB, PS, rwh, rwl, rb, crossB, gp);
        k_gnred<<<64, 256, 0, stream>>>(gp, stats);
        k_gnapply<<<(int)(((long)2 * Cc * SP / 4) / 256), 256, 0, stream>>>(
            hin, crossB, stats, gnw + layer * 128, gnb + layer * 128, out,
            bp, layer == 1);
        hin = out;
    }
    k_bnfin<<<1, 256, 0, stream>>>(bp, bnw, bnb, bnss);
    k_bnrelu<<<(int)(((long)2 * Cc * SP / 4) / 256), 256, 0, stream>>>(out, bnss, out);
}

// Round 13
// 808.605 us; speedup vs baseline: 1.0219x; 1.0219x over previous
//
#include <hip/hip_runtime.h>
#include <math.h>

// Problem constants
constexpr int Cc = 128;          // channels
constexpr int Dd = 48, Hh = 48, Ww = 48;
constexpr int SP = Dd * Hh * Ww; // 110592 voxels per batch
constexpr int NV = 2 * SP;       // 221184 total voxels
constexpr float EPSV = 1e-5f;

typedef __attribute__((ext_vector_type(8))) short short8;
typedef __attribute__((ext_vector_type(4))) float f32x4;

static __device__ __forceinline__ ushort f2bf(float f) {
    uint u = __float_as_uint(f);
    uint r = (u + 0x7fffu + ((u >> 16) & 1u)) >> 16;   // RNE
    return (ushort)r;
}

// ---------------------------------------------------------------- prep
__global__ void k_prep(const float* __restrict__ th, const float* __restrict__ ph,
                       const float* __restrict__ gw, const float* __restrict__ rw,
                       ushort* __restrict__ wtb, ushort* __restrict__ rwh,
                       ushort* __restrict__ rwl) {
    int tid = threadIdx.x;
    for (int i = tid; i < 192 * 128; i += 256) {
        int o = i >> 7, c = i & 127;
        float v = (o < 64)  ? th[o * 128 + c]
                : (o < 128) ? ph[(o - 64) * 128 + c]
                            : gw[(o - 128) * 128 + c];
        wtb[i] = f2bf(v);
    }
    // rW hi/lo split, [c][g] layout (same as input r_w)
    for (int i = tid; i < 128 * 64; i += 256) {
        float v = rw[i];
        ushort hh = f2bf(v);
        rwh[i] = hh;
        rwl[i] = f2bf(v - __uint_as_float((uint)hh << 16));
    }
}

// ---------------------------------------------------------------- projections (MFMA)
// 128 voxels/block, 512 threads — R10 measured-best form (R11's operand swap
// reverted: its per-lane 8B stores had 128B lane stride = scattered; the
// "scalar" layout coalesces 32B per quad-group). unroll 2 for nt-loop ILP.
__global__ __launch_bounds__(512) void k_proj(
        const float* __restrict__ h, const ushort* __restrict__ wtb,
        const float* __restrict__ tb, const float* __restrict__ pb,
        const float* __restrict__ gb,
        ushort* __restrict__ tO, ushort* __restrict__ pO, ushort* __restrict__ gO) {
    __shared__ __align__(16) uint wl[192 * 64];   // 48 KB, [o][c-pairs] swizzled
    int tid = threadIdx.x;
    const uint* wu = (const uint*)wtb;
    for (int i = tid; i < 192 * 64; i += 512) {
        int o = i >> 6, dw = i & 63;
        wl[(o << 6) + ((((dw >> 2) ^ (o & 15)) << 2)) + (dw & 3)] = wu[i];
    }
    int blk = blockIdx.x;                         // 1728
    int b = blk / (SP / 128);
    int vsp0 = (blk % (SP / 128)) * 128;
    const float* hb = h + (size_t)b * Cc * SP;
    int lane = tid & 63, wv = tid >> 6;           // wv 0..7
    int m = lane & 15, quad = lane >> 4;
    int vg = vsp0 + wv * 16 + m;
    short8 afr[4];
#pragma unroll
    for (int ks = 0; ks < 4; ++ks) {
        int c0 = ks * 32 + quad * 8;
        float xv[8];
#pragma unroll
        for (int j = 0; j < 8; ++j) xv[j] = hb[(size_t)(c0 + j) * SP + vg];
        union { short8 v; ushort e[8]; } u;
#pragma unroll
        for (int j = 0; j < 8; ++j) u.e[j] = f2bf(xv[j]);
        afr[ks] = u.v;
    }
    __syncthreads();
    int vox = b * SP + vsp0 + wv * 16 + quad * 4;
#pragma unroll 2
    for (int nt = 0; nt < 12; ++nt) {
        int o16 = (nt & 3) * 16 + m;
        float bv = (nt < 4) ? tb[o16] : (nt < 8) ? pb[o16] : gb[o16];
        f32x4 acc = {bv, bv, bv, bv};
        int o = nt * 16 + m;
#pragma unroll
        for (int ks = 0; ks < 4; ++ks) {
            int chunk = ks * 4 + quad;
            short8 bfr = *(const short8*)&wl[(o << 6) + ((chunk ^ (o & 15)) << 2)];
            acc = __builtin_amdgcn_mfma_f32_16x16x32_bf16(afr[ks], bfr, acc, 0, 0, 0);
        }
        ushort* ob = (nt < 4) ? tO : (nt < 8) ? pO : gO;
#pragma unroll
        for (int r = 0; r < 4; ++r) ob[(size_t)(vox + r) * 64 + o16] = f2bf(acc[r]);
    }
}

// ---------------------------------------------------------------- scores (MFMA, 3 axes)
// Writes E = bf16(exp(S)) directly (masked diag -> 0) + per-row sums PS = sum(e).
// ysum loads E fragments straight from global; normalization applied in k_cross.
__global__ __launch_bounds__(256) void k_scores(
        const ushort* __restrict__ t, const ushort* __restrict__ p,
        ushort* __restrict__ fb16, float* __restrict__ PS) {
    __shared__ __align__(16) uint sl[4 * 3072];
    int blk = blockIdx.x;                         // 3456 = 3 axes * 1152
    int axis = blk / 1152, rem = blk % 1152;
    int wv = threadIdx.x >> 6, lane = threadIdx.x & 63;
    int L = rem * 4 + wv;
    int b = L / 2304, rr = L % 2304, i = rr / 48, j = rr % 48;
    int stride, vsp0;
    if (axis == 0)      { stride = 2304; vsp0 = i * 48 + j; }
    else if (axis == 1) { stride = 48;   vsp0 = i * 2304 + j; }
    else                { stride = 1;    vsp0 = i * 2304 + j * 48; }
    int vox0 = b * SP + vsp0;
    ushort* f = fb16 + (size_t)axis * NV * 48;
    float* ps = PS + (size_t)axis * NV;
    uint* tl = &sl[wv * 3072];
    uint* pl = tl + 1536;
    const uint* tu = (const uint*)t;
    const uint* pu = (const uint*)p;
#pragma unroll 4
    for (int it = 0; it < 24; ++it) {
        int idx = it * 64 + lane;
        int r = idx >> 5, dw = idx & 31;
        int gaddr = (vox0 + r * stride) * 32 + dw;
        int laddr = (r << 5) + (((dw >> 2) ^ (r & 7)) << 2) + (dw & 3);
        tl[laddr] = tu[gaddr];
        pl[laddr] = pu[gaddr];
    }
    __syncthreads();
    int m = lane & 15, quad = lane >> 4;
    short8 afr[3][2];
#pragma unroll
    for (int mt = 0; mt < 3; ++mt)
#pragma unroll
        for (int ks = 0; ks < 2; ++ks) {
            int r = mt * 16 + m, chunk = ks * 4 + quad;
            afr[mt][ks] = *(const short8*)&tl[(r << 5) + ((chunk ^ (r & 7)) << 2)];
        }
    f32x4 acc[3][3];
#pragma unroll
    for (int mt = 0; mt < 3; ++mt)
#pragma unroll
        for (int nt = 0; nt < 3; ++nt) acc[mt][nt] = (f32x4){0.f, 0.f, 0.f, 0.f};
#pragma unroll
    for (int nt = 0; nt < 3; ++nt)
#pragma unroll
        for (int ks = 0; ks < 2; ++ks) {
            int a = nt * 16 + m, chunk = ks * 4 + quad;
            short8 bfr = *(const short8*)&pl[(a << 5) + ((chunk ^ (a & 7)) << 2)];
#pragma unroll
            for (int mt = 0; mt < 3; ++mt)
                acc[mt][nt] = __builtin_amdgcn_mfma_f32_16x16x32_bf16(
                    afr[mt][ks], bfr, acc[mt][nt], 0, 0, 0);
        }
    bool mask = (axis != 0);
    float esum[3][4];
#pragma unroll
    for (int mt = 0; mt < 3; ++mt)
#pragma unroll
        for (int r4 = 0; r4 < 4; ++r4) esum[mt][r4] = 0.f;
#pragma unroll
    for (int mt = 0; mt < 3; ++mt)
#pragma unroll
        for (int nt = 0; nt < 3; ++nt)
#pragma unroll
            for (int r4 = 0; r4 < 4; ++r4) {
                int r = mt * 16 + quad * 4 + r4;
                int a = nt * 16 + m;
                float e = (mask && a == r) ? 0.f : __expf(acc[mt][nt][r4]);
                f[(size_t)(vox0 + r * stride) * 48 + a] = f2bf(e);
                esum[mt][r4] += e;
            }
    // per-row exp-sum: reduce across the 16 lanes (m) of each quad-group
#pragma unroll
    for (int mt = 0; mt < 3; ++mt)
#pragma unroll
        for (int r4 = 0; r4 < 4; ++r4) {
            float s = esum[mt][r4];
#pragma unroll
            for (int o = 8; o; o >>= 1) s += __shfl_xor(s, o, 64);
            if (m == 0) {
                int r = mt * 16 + quad * 4 + r4;
                ps[vox0 + r * stride] = s;
            }
        }
}

// ---------------------------------------------------------------- weighted sum (MFMA)
// Y'[48x64] (+)= E[48x48] . G[48x64] per line (UNNORMALIZED; inv applied in k_cross).
// E fragments loaded DIRECTLY from global (16B-aligned, L2-hot; K-pad chunks -> 0).
// Only G (true transpose gather) stages through LDS: 8KB/wave.
__global__ __launch_bounds__(128) void k_ysum(
        const ushort* __restrict__ wgt, const ushort* __restrict__ g,
        float* __restrict__ y, int axis, int accum) {
    __shared__ __align__(16) uint sl[2 * 2048];   // per-wave gl 2048 dw (8 KB)
    int wv = threadIdx.x >> 6, lane = threadIdx.x & 63;
    uint* gl = &sl[wv * 2048];
    int L = blockIdx.x * 2 + wv;                  // 0..4607
    int b = L / 2304, rr = L % 2304, i = rr / 48, j = rr % 48;
    int stride, vsp0;
    if (axis == 0)      { stride = 2304; vsp0 = i * 48 + j; }
    else if (axis == 1) { stride = 48;   vsp0 = i * 2304 + j; }
    else                { stride = 1;    vsp0 = i * 2304 + j * 48; }
    int vox0 = b * SP + vsp0;
    int m = lane & 15, quad = lane >> 4;
    // E fragments direct from global: row r, cols chunk*8..+7 (16B aligned: r*96+chunk*16)
    short8 afr[3][2];
#pragma unroll
    for (int mt = 0; mt < 3; ++mt)
#pragma unroll
        for (int ks = 0; ks < 2; ++ks) {
            int chunk = ks * 4 + quad;
            short8 v = (short8){0, 0, 0, 0, 0, 0, 0, 0};
            if (chunk < 6) {
                int r = mt * 16 + m;
                v = *(const short8*)&wgt[(size_t)(vox0 + r * stride) * 48 + chunk * 8];
            }
            afr[mt][ks] = v;
        }
    // gl zero-pad chunks 6,7 (a>=48): avoid 0 x stale-NaN = NaN
#pragma unroll
    for (int it = 0; it < 8; ++it) {
        int idx = it * 64 + lane;
        int s = idx >> 3, dwp = 24 + (idx & 7);
        gl[(s << 5) + ((((dwp >> 2)) ^ (s & 7)) << 2) + (dwp & 3)] = 0;
    }
    // G transpose staging: read [a][s-pairs] dwords, shfl-pair a/a^1, write [s][a-pairs]
    const uint* gu = (const uint*)g;
#pragma unroll 4
    for (int it = 0; it < 24; ++it) {
        int a = it * 2 + (lane >> 5);
        int dw = lane & 31;
        uint v = gu[(size_t)(vox0 + a * stride) * 32 + dw];
        uint w = (uint)__shfl_xor((int)v, 32, 64);
        uint dst; int s;
        if (lane < 32) { s = dw * 2;     dst = (v & 0xffffu) | (w << 16); }
        else           { s = dw * 2 + 1; dst = (w >> 16) | (v & 0xffff0000u); }
        int adw = it;
        gl[(s << 5) + ((((adw >> 2)) ^ (s & 7)) << 2) + (adw & 3)] = dst;
    }
    // per-wave LDS slice: no __syncthreads needed (in-wave DS ordering)
    f32x4 acc[3][4];
#pragma unroll
    for (int mt = 0; mt < 3; ++mt)
#pragma unroll
        for (int nt = 0; nt < 4; ++nt) acc[mt][nt] = (f32x4){0.f, 0.f, 0.f, 0.f};
#pragma unroll
    for (int nt = 0; nt < 4; ++nt)
#pragma unroll
        for (int ks = 0; ks < 2; ++ks) {
            int s = nt * 16 + m, chunk = ks * 4 + quad;
            short8 bfr = *(const short8*)&gl[(s << 5) + ((chunk ^ (s & 7)) << 2)];
#pragma unroll
            for (int mt = 0; mt < 3; ++mt)
                acc[mt][nt] = __builtin_amdgcn_mfma_f32_16x16x32_bf16(
                    afr[mt][ks], bfr, acc[mt][nt], 0, 0, 0);
        }
#pragma unroll
    for (int mt = 0; mt < 3; ++mt)
#pragma unroll
        for (int r4 = 0; r4 < 4; ++r4) {
            int r = mt * 16 + quad * 4 + r4;
#pragma unroll
            for (int nt = 0; nt < 4; ++nt) {
                size_t addr = (size_t)(vox0 + r * stride) * 64 + nt * 16 + m;
                float pr = accum ? y[addr] : 0.f;
                y[addr] = pr + acc[mt][nt][r4];
            }
        }
}

// ---------------------------------------------------------------- cross proj (MFMA, hi/lo bf16)
// A-rows normalized on load: y_row * 1/(PS0+PS1+PS2). + fused GN partials -> gp.
__global__ __launch_bounds__(256) void k_cross(
        const float* __restrict__ y, const float* __restrict__ PS,
        const ushort* __restrict__ rwh, const ushort* __restrict__ rwl,
        const float* __restrict__ rb,
        float* __restrict__ cross, float* __restrict__ gp) {
    __shared__ __align__(16) uint sl[8192];       // 32 KB
    int tid = threadIdx.x;
    int blk = blockIdx.x;                         // 3456
    int b = blk / (SP / 64);
    int sp64 = blk % (SP / 64);                   // 0..1727
    int vsp0 = sp64 * 64;
    long vox0 = (long)b * SP + vsp0;
    const uint* wh = (const uint*)rwh;
    const uint* wlg = (const uint*)rwl;
    for (int i = tid; i < 8192; i += 256) {
        int t = i >> 12, rr = (i >> 5) & 127, dw = i & 31;
        uint v = (t == 0) ? wh[rr * 32 + dw] : wlg[rr * 32 + dw];
        sl[(t << 12) + (rr << 5) + (((dw >> 2) ^ (rr & 7)) << 2) + (dw & 3)] = v;
    }
    int lane = tid & 63, wv = tid >> 6;
    int m = lane & 15, quad = lane >> 4;
    short8 ah[2], al[2];
    long vrow = vox0 + wv * 16 + m;
    const float* yrow = y + vrow * 64;
    float iv = 1.f / (PS[vrow] + PS[NV + vrow] + PS[2 * NV + vrow]);
#pragma unroll
    for (int ks = 0; ks < 2; ++ks) {
        float4 v0 = *(const float4*)(yrow + ks * 32 + quad * 8);
        float4 v1 = *(const float4*)(yrow + ks * 32 + quad * 8 + 4);
        float xv[8] = {v0.x * iv, v0.y * iv, v0.z * iv, v0.w * iv,
                       v1.x * iv, v1.y * iv, v1.z * iv, v1.w * iv};
        union { short8 v; ushort e[8]; } uh, ul;
#pragma unroll
        for (int j = 0; j < 8; ++j) {
            ushort hh = f2bf(xv[j]);
            uh.e[j] = hh;
            ul.e[j] = f2bf(xv[j] - __uint_as_float((uint)hh << 16));
        }
        ah[ks] = uh.v; al[ks] = ul.v;
    }
    f32x4 acc[8];
#pragma unroll
    for (int nt = 0; nt < 8; ++nt) {
        float bv = rb[nt * 16 + m];
        acc[nt] = (f32x4){bv, bv, bv, bv};
    }
    __syncthreads();
#pragma unroll
    for (int nt = 0; nt < 8; ++nt) {
        int r = nt * 16 + m;
#pragma unroll
        for (int ks = 0; ks < 2; ++ks) {
            int chunk = ks * 4 + quad;
            int off = (r << 5) + ((chunk ^ (r & 7)) << 2);
            short8 bh = *(const short8*)&sl[off];
            short8 bl = *(const short8*)&sl[4096 + off];
            acc[nt] = __builtin_amdgcn_mfma_f32_16x16x32_bf16(ah[ks], bh, acc[nt], 0, 0, 0);
            acc[nt] = __builtin_amdgcn_mfma_f32_16x16x32_bf16(al[ks], bh, acc[nt], 0, 0, 0);
            acc[nt] = __builtin_amdgcn_mfma_f32_16x16x32_bf16(ah[ks], bl, acc[nt], 0, 0, 0);
        }
    }
    __syncthreads();
    int sv = wv * 4 + quad;
#pragma unroll
    for (int nt = 0; nt < 8; ++nt) {
        int c = nt * 16 + m;
        *(f32x4*)&sl[((c << 4) | (sv ^ (c & 15))) << 2] = acc[nt];
    }
    __syncthreads();
#pragma unroll
    for (int it = 0; it < 8; ++it) {
        int idx = it * 256 + tid;
        int c = idx >> 4, s16 = idx & 15;
        float4 val = *(const float4*)&sl[((c << 4) | (s16 ^ (c & 15))) << 2];
        *(float4*)&cross[((long)b * Cc + c) * SP + vsp0 + s16 * 4] = val;
        float s  = val.x + val.y + val.z + val.w;
        float ss = val.x * val.x + val.y * val.y + val.z * val.z + val.w * val.w;
#pragma unroll
        for (int o = 32; o; o >>= 1) { s += __shfl_xor(s, o, 64); ss += __shfl_xor(ss, o, 64); }
        if (lane == 0) {
            int bg = b * 32 + it * 4 + wv;
            gp[(size_t)(bg * 2) * 1728 + sp64] = s;
            gp[(size_t)(bg * 2 + 1) * 1728 + sp64] = ss;
        }
    }
}

// ---------------------------------------------------------------- GN reduce (scatter -> stats)
__global__ __launch_bounds__(256) void k_gnred(
        const float* __restrict__ gp, float* __restrict__ stats) {
    int g = blockIdx.x;          // 64
    const float* r0 = gp + (size_t)(g * 2) * 1728;
    const float* r1 = r0 + 1728;
    float s = 0.f, ss = 0.f;
    for (int t = threadIdx.x; t < 1728; t += 256) { s += r0[t]; ss += r1[t]; }
#pragma unroll
    for (int o = 32; o; o >>= 1) { s += __shfl_xor(s, o, 64); ss += __shfl_xor(ss, o, 64); }
    __shared__ float rs[4], rss[4];
    int wv = threadIdx.x >> 6;
    if ((threadIdx.x & 63) == 0) { rs[wv] = s; rss[wv] = ss; }
    __syncthreads();
    if (threadIdx.x == 0) {
        float S = rs[0] + rs[1] + rs[2] + rs[3];
        float SS = rss[0] + rss[1] + rss[2] + rss[3];
        float n = 4.f * SP;
        float mu = S / n, var = SS / n - mu * mu;
        stats[g * 2] = mu;
        stats[g * 2 + 1] = rsqrtf(var + EPSV);
    }
}

// ---------------------------------------------------------------- GN apply (+ BN partial scatter)
__global__ __launch_bounds__(256) void k_gnapply(
        const float* __restrict__ hin, const float* __restrict__ cross,
        const float* __restrict__ stats, const float* __restrict__ gw,
        const float* __restrict__ gb, float* __restrict__ hout,
        float* __restrict__ bp, int doBN) {
    __shared__ float rs[4], rss[4];
    long q = ((long)blockIdx.x * 256 + threadIdx.x) * 4;
    int c = (int)((q / SP) & 127);
    int b = (int)(q / ((long)Cc * SP));
    int bg = b * 32 + (c >> 2);
    float mu = stats[bg * 2], inv = stats[bg * 2 + 1];
    float sc = inv * gw[c], sh = gb[c] - mu * sc;
    float4 cv = *(const float4*)(cross + q);
    float4 hv = *(const float4*)(hin + q);
    float4 o = make_float4(hv.x + cv.x * sc + sh, hv.y + cv.y * sc + sh,
                           hv.z + cv.z * sc + sh, hv.w + cv.w * sc + sh);
    *(float4*)(hout + q) = o;
    if (doBN) {
        float s  = o.x + o.y + o.z + o.w;
        float ss = o.x * o.x + o.y * o.y + o.z * o.z + o.w * o.w;
#pragma unroll
        for (int off = 32; off; off >>= 1) { s += __shfl_xor(s, off, 64); ss += __shfl_xor(ss, off, 64); }
        if ((threadIdx.x & 63) == 0) { rs[threadIdx.x >> 6] = s; rss[threadIdx.x >> 6] = ss; }
        __syncthreads();
        if (threadIdx.x == 0) {
            float S = rs[0] + rs[1] + rs[2] + rs[3];
            float SS = rss[0] + rss[1] + rss[2] + rss[3];
            int l = blockIdx.x % 108;             // 108 blocks per (b,c)
            int contrib = b * 108 + l;            // 0..215
            bp[(size_t)(c * 2) * 216 + contrib] = S;
            bp[(size_t)(c * 2 + 1) * 216 + contrib] = SS;
        }
    }
}

// ---------------------------------------------------------------- BN finalize (scatter -> scale/shift)
__global__ void k_bnfin(const float* __restrict__ bp, const float* __restrict__ bw,
                        const float* __restrict__ bb, float* __restrict__ ssout) {
    __shared__ float rows[256];
    int tid = threadIdx.x;   // 256: one row of 216 per thread
    float acc = 0.f;
    const float* r = bp + (size_t)tid * 216;
    for (int t = 0; t < 216; ++t) acc += r[t];
    rows[tid] = acc;
    __syncthreads();
    if (tid < 128) {
        float s = rows[tid * 2], qq = rows[tid * 2 + 1];
        float n = 2.f * SP;
        float mu = s / n, var = qq / n - mu * mu;
        float inv = rsqrtf(var + EPSV);
        float a1 = inv * bw[tid];
        ssout[tid * 2] = a1;
        ssout[tid * 2 + 1] = bb[tid] - mu * a1;
    }
}

__global__ __launch_bounds__(256) void k_bnrelu(
        const float* __restrict__ h, const float* __restrict__ ssin,
        float* __restrict__ out) {
    long q = ((long)blockIdx.x * 256 + threadIdx.x) * 4;
    int c = (int)((q / SP) & 127);
    float a1 = ssin[c * 2], a0 = ssin[c * 2 + 1];
    float4 v = *(const float4*)(h + q);
    float4 o = make_float4(fmaxf(v.x * a1 + a0, 0.f), fmaxf(v.y * a1 + a0, 0.f),
                           fmaxf(v.z * a1 + a0, 0.f), fmaxf(v.w * a1 + a0, 0.f));
    *(float4*)(out + q) = o;
}

// ---------------------------------------------------------------- launch
extern "C" void kernel_launch(void* const* d_in, const int* in_sizes, int n_in,
                              void* d_out, int out_size, void* d_ws, size_t ws_size,
                              hipStream_t stream) {
    const float* x   = (const float*)d_in[0];
    const float* thw = (const float*)d_in[1];
    const float* thb = (const float*)d_in[2];
    const float* phw = (const float*)d_in[3];
    const float* phb = (const float*)d_in[4];
    const float* gww = (const float*)d_in[5];
    const float* gwb = (const float*)d_in[6];
    const float* rw  = (const float*)d_in[7];
    const float* rb  = (const float*)d_in[8];
    const float* gnw = (const float*)d_in[9];
    const float* gnb = (const float*)d_in[10];
    const float* bnw = (const float*)d_in[11];
    const float* bnb = (const float*)d_in[12];

    float* ws    = (float*)d_ws;
    ushort* rwh  = (ushort*)ws;               // 8192 bf16 (hi)
    ushort* rwl  = rwh + 8192;                // 8192 bf16 (lo)
    float* stats = ws + 10240;                // 128
    float* bnss  = ws + 10368;                // 256
    ushort* wTb  = (ushort*)(ws + 16384);     // 24576 bf16 ([o][c] row-major)
    ushort* tB16 = (ushort*)(ws + 32768);     // NV*64 bf16
    ushort* pB16 = tB16 + (size_t)NV * 64;
    ushort* gB16 = pB16 + (size_t)NV * 64;
    float* yB    = ws + 32768 + (3 * (size_t)NV * 64) / 2;  // NV*64 fp32
    float* crossB = yB + (size_t)NV * 64;     // NV*128 fp32
    ushort* fb16 = (ushort*)crossB;           // 3*NV*48 bf16 (dead before cross writes)
    float* gp    = crossB + (size_t)NV * 128; // 64*2*1728 fp32 (GN scatter)
    float* bp    = gp + 221184;               // 128*2*216 fp32 (BN scatter)
    float* PS    = bp + 55296;                // 3*NV fp32
    float* out = (float*)d_out;

    k_prep<<<1, 256, 0, stream>>>(thw, phw, gww, rw, wTb, rwh, rwl);

    const float* hin = x;
    for (int layer = 0; layer < 2; ++layer) {
        k_proj<<<NV / 128, 512, 0, stream>>>(hin, wTb, thb, phb, gwb, tB16, pB16, gB16);
        k_scores<<<3456, 256, 0, stream>>>(tB16, pB16, fb16, PS);
        for (int ax = 0; ax < 3; ++ax)
            k_ysum<<<2304, 128, 0, stream>>>(fb16 + (size_t)ax * NV * 48,
                gB16, yB, ax, ax > 0);
        k_cross<<<NV / 64, 256, 0, stream>>>(yB, PS, rwh, rwl, rb, crossB, gp);
        k_gnred<<<64, 256, 0, stream>>>(gp, stats);
        k_gnapply<<<(int)(((long)2 * Cc * SP / 4) / 256), 256, 0, stream>>>(
            hin, crossB, stats, gnw + layer * 128, gnb + layer * 128, out,
            bp, layer == 1);
        hin = out;
    }
    k_bnfin<<<1, 256, 0, stream>>>(bp, bnw, bnb, bnss);
    k_bnrelu<<<(int)(((long)2 * Cc * SP / 4) / 256), 256, 0, stream>>>(out, bnss, out);
}